// Round 7
// baseline (614.020 us; speedup 1.0000x reference)
//
#include <hip/hip_runtime.h>
#include <hip/hip_bf16.h>

// RelativeGlobalAttention: B=2, S=2048, D=512, H=8, DH=64, MAX_SEQ=2048
// out0 = attention output (B,S,D); out1 = attn probs (B,H,S,S); concatenated in d_out.
//
// Identity: srel[l,k] = q[l].E[2047-l+k] for k<=l, else 0.
// logits = (QK^T + srel)/8; causal mask => masked probs exactly 0.
// No-max softmax: exp(v)/sum(exp(v)) == reference softmax up to fp32 rounding.
//
// R7 vs R6: fix the triangular load imbalance (measured 40% occupancy at
// exactly-one-residency). Strip pairing (p, 127-p): per-block work constant
// (33+-1 tiles). Two kernels: lsum (light, computes linv in-block) and
// emit+PV. 512-thr blocks, grid (16,64)=1024 = 4 blocks/CU full residency,
// each wave gets a fixed slot count -> no drain.

namespace {
constexpr int kS  = 2048;
constexpr int kD  = 512;
constexpr int kH  = 8;
constexpr int kDH = 64;
constexpr int kB  = 2;

typedef __attribute__((ext_vector_type(8))) short short8;   // 8 x bf16
typedef __attribute__((ext_vector_type(4))) float f32x4;
}

// compiler+HW fence for wave-private LDS write->read / read->write ordering
// (same-wave LDS ops execute in order; the fence stops COMPILER reordering,
// which caused R4's failure). No sched_barrier: leave ALU scheduling free.
#define WAVE_LDS_FENCE() asm volatile("s_waitcnt lgkmcnt(0)" ::: "memory")

__device__ __forceinline__ f32x4 mfma16(short8 a, short8 b, f32x4 c) {
    return __builtin_amdgcn_mfma_f32_16x16x32_bf16(a, b, c, 0, 0, 0);
}

__device__ __forceinline__ short bfbits(float f) {
    __hip_bfloat16 h = __float2bfloat16(f);
    return *reinterpret_cast<short*>(&h);
}

// ---------------------------------------------------------------------------
// conv: W (512x512 fp32 row-major) -> Wt (bf16 col-major [c][k]) x4; E -> bf16
// ---------------------------------------------------------------------------
__global__ __launch_bounds__(256)
void convw_kernel(const float* __restrict__ Wq, const float* __restrict__ Wk,
                  const float* __restrict__ Wv, const float* __restrict__ Wo,
                  const float* __restrict__ E,
                  ushort* __restrict__ Wqt, ushort* __restrict__ Wkt,
                  ushort* __restrict__ Wvt, ushort* __restrict__ Wot,
                  ushort* __restrict__ eb)
{
    const int z = blockIdx.z;
    const int tid = threadIdx.x;
    if (z == 4) {   // E: 2048x64 = 131072 elems
        const int idx = ((blockIdx.y * 8 + blockIdx.x) * 256 + tid) * 8;
        const float4 x = *reinterpret_cast<const float4*>(E + idx);
        const float4 y = *reinterpret_cast<const float4*>(E + idx + 4);
        short8 r;
        r[0] = bfbits(x.x); r[1] = bfbits(x.y); r[2] = bfbits(x.z); r[3] = bfbits(x.w);
        r[4] = bfbits(y.x); r[5] = bfbits(y.y); r[6] = bfbits(y.z); r[7] = bfbits(y.w);
        *reinterpret_cast<short8*>(eb + idx) = r;
        return;
    }
    const float* W = (z == 0) ? Wq : (z == 1) ? Wk : (z == 2) ? Wv : Wo;
    ushort* Wt = (z == 0) ? Wqt : (z == 1) ? Wkt : (z == 2) ? Wvt : Wot;

    __shared__ float Ws[64][65];
    const int k0 = blockIdx.x * 64;
    const int c0 = blockIdx.y * 64;
    const int cc = tid & 63;
    const int rq = tid >> 6;
    #pragma unroll
    for (int ii = 0; ii < 16; ++ii) {
        const int r = ii * 4 + rq;
        Ws[r][cc] = W[(size_t)(k0 + r) * kD + c0 + cc];
    }
    __syncthreads();
    #pragma unroll
    for (int ii = 0; ii < 16; ++ii) {
        const int r = ii * 4 + rq;
        Wt[(size_t)(c0 + r) * kD + k0 + cc] = (ushort)bfbits(Ws[cc][r]);
    }
}

// q_in/k_in/v_in fp32 (B,S,D) -> bf16
__global__ __launch_bounds__(256)
void cvta_kernel(const float* __restrict__ q, const float* __restrict__ k,
                 const float* __restrict__ v,
                 ushort* __restrict__ qb, ushort* __restrict__ kb,
                 ushort* __restrict__ vb)
{
    const int z = blockIdx.z;
    const float* src = (z == 0) ? q : (z == 1) ? k : v;
    ushort* dst = (z == 0) ? qb : (z == 1) ? kb : vb;
    const int idx = (blockIdx.x * 256 + threadIdx.x) * 8;
    const float4 x = *reinterpret_cast<const float4*>(src + idx);
    const float4 y = *reinterpret_cast<const float4*>(src + idx + 4);
    short8 r;
    r[0] = bfbits(x.x); r[1] = bfbits(x.y); r[2] = bfbits(x.z); r[3] = bfbits(x.w);
    r[4] = bfbits(y.x); r[5] = bfbits(y.y); r[6] = bfbits(y.z); r[7] = bfbits(y.w);
    *reinterpret_cast<short8*>(dst + idx) = r;
}

// ---------------------------------------------------------------------------
// MFMA GEMM core (unchanged)
// ---------------------------------------------------------------------------
template<int MODE>
__device__ __forceinline__
void gemm_core(const ushort* __restrict__ A, const ushort* __restrict__ Wt,
               const float* __restrict__ bias, void* __restrict__ out)
{
    const int tid  = threadIdx.x;
    const int w    = tid >> 6;
    const int lane = tid & 63;
    const int g    = lane >> 4;
    const int n15  = lane & 15;
    const int r0   = blockIdx.x * 64 + w * 16;
    const int c0   = blockIdx.y * 32;

    f32x4 acc0 = {0.f, 0.f, 0.f, 0.f};
    f32x4 acc1 = {0.f, 0.f, 0.f, 0.f};
    const ushort* arow = A  + (size_t)(r0 + n15) * kD + g * 8;
    const ushort* b0p  = Wt + (size_t)(c0 + n15) * kD + g * 8;
    const ushort* b1p  = Wt + (size_t)(c0 + 16 + n15) * kD + g * 8;

    #pragma unroll 4
    for (int k0 = 0; k0 < kD; k0 += 32) {
        const short8 a  = *reinterpret_cast<const short8*>(arow + k0);
        const short8 b0 = *reinterpret_cast<const short8*>(b0p + k0);
        const short8 b1 = *reinterpret_cast<const short8*>(b1p + k0);
        acc0 = mfma16(a, b0, acc0);
        acc1 = mfma16(a, b1, acc1);
    }

    #pragma unroll
    for (int cg = 0; cg < 2; ++cg) {
        const f32x4 acc = cg ? acc1 : acc0;
        const int c = c0 + cg * 16 + n15;
        const float bb = bias[c];
        const int h = c >> 6, d = c & (kDH - 1);
        #pragma unroll
        for (int j = 0; j < 4; ++j) {
            const int r = r0 + g * 4 + j;
            const float val = acc[j] + bb;
            const int b = r >> 11, s2 = r & (kS - 1);
            if (MODE == 0) {
                ((float*)out)[(size_t)r * kD + c] = val;
            } else if (MODE == 1) {
                ((ushort*)out)[((size_t)(b * kH + h) * kS + s2) * kDH + d] = (ushort)bfbits(val);
            } else {
                ((ushort*)out)[((size_t)(b * kH + h) * kDH + d) * kS + s2] = (ushort)bfbits(val);
            }
        }
    }
}

__global__ __launch_bounds__(256)
void gemm_qkv_kernel(const ushort* __restrict__ qb, const ushort* __restrict__ kb,
                     const ushort* __restrict__ vb,
                     const ushort* __restrict__ Wqt, const ushort* __restrict__ Wkt,
                     const ushort* __restrict__ Wvt,
                     const float* __restrict__ bq, const float* __restrict__ bk,
                     const float* __restrict__ bv,
                     ushort* __restrict__ qh, ushort* __restrict__ kh,
                     ushort* __restrict__ vt)
{
    const int z = blockIdx.z;
    const ushort* A    = (z == 0) ? qb  : (z == 1) ? kb  : vb;
    const ushort* Wt   = (z == 0) ? Wqt : (z == 1) ? Wkt : Wvt;
    const float*  bias = (z == 0) ? bq  : (z == 1) ? bk  : bv;
    void*         out  = (z == 0) ? (void*)qh : (z == 1) ? (void*)kh : (void*)vt;
    if (z == 2) gemm_core<2>(A, Wt, bias, out);
    else        gemm_core<1>(A, Wt, bias, out);
}

__global__ __launch_bounds__(256)
void gemm_o_kernel(const ushort* __restrict__ ohb, const ushort* __restrict__ Wot,
                   const float* __restrict__ bo, float* __restrict__ out)
{
    gemm_core<0>(ohb, Wot, bo, out);
}

// ---------------------------------------------------------------------------
// Attention kernel A: row sums -> linv. Block = (bh, pair p): strips p and
// 127-p in two sequential phases; 8 waves x 512 thr; wave w takes tiles
// t = w, w+8, ... Per-block work == const. grid (16,64) = full residency.
// ---------------------------------------------------------------------------
__global__ __launch_bounds__(512, 8)
void attn_lsum_kernel(const ushort* __restrict__ qh, const ushort* __restrict__ kh,
                      const ushort* __restrict__ eb, float* __restrict__ linvg)
{
    __shared__ float lsum_s[128];                // 8 waves x 16 rows

    const int bh   = blockIdx.x;
    const int p    = blockIdx.y;
    const int tid  = threadIdx.x;
    const int w    = tid >> 6;
    const int lane = tid & 63;
    const int g    = lane >> 4;
    const int n15  = lane & 15;
    const size_t bhS = (size_t)bh * kS;

    // diagonal-gather constants: R[lr][ki] = qe[lr][ki-lr+15] lives at
    // col-lane (d&15), register nt + (d>=16), d = n15 + 15 - lr.
    int  srcl[4];
    bool condj[4];
    #pragma unroll
    for (int j = 0; j < 4; ++j) {
        const int d = n15 + 15 - (g * 4 + j);
        srcl[j]  = (lane & 48) | (d & 15);
        condj[j] = (d >= 16);
    }

    #pragma unroll
    for (int ph = 0; ph < 2; ++ph) {
        const int s  = ph ? (127 - p) : p;
        const int l0 = s * 16;
        const int T  = (s >> 2) + 1;             // causal 64-wide tiles

        const ushort* qrow = qh + (bhS + l0 + n15) * kDH;
        const short8 aq0 = *reinterpret_cast<const short8*>(qrow + g * 8);
        const short8 aq1 = *reinterpret_cast<const short8*>(qrow + 32 + g * 8);

        float lsum[4] = {0.f, 0.f, 0.f, 0.f};
        for (int t = w; t < T; t += 8) {
            const int k0 = t * 64;
            float sl[4][4];
            #pragma unroll
            for (int nt = 0; nt < 4; ++nt) {
                const ushort* krow = kh + (bhS + k0 + nt * 16 + n15) * kDH;
                f32x4 acc = {0.f, 0.f, 0.f, 0.f};
                acc = mfma16(aq0, *reinterpret_cast<const short8*>(krow + g * 8), acc);
                acc = mfma16(aq1, *reinterpret_cast<const short8*>(krow + 32 + g * 8), acc);
                #pragma unroll
                for (int j = 0; j < 4; ++j) sl[nt][j] = acc[j];
            }
            const int m_lo = 2032 + k0 - l0;
            f32x4 qe[5];
            #pragma unroll
            for (int nt = 0; nt < 5; ++nt) {
                int er = m_lo + nt * 16 + n15;
                if (er > kS - 1) er = kS - 1;    // clamped rows only feed masked elems
                const ushort* erow = eb + (size_t)er * kDH;
                f32x4 acc = {0.f, 0.f, 0.f, 0.f};
                acc = mfma16(aq0, *reinterpret_cast<const short8*>(erow + g * 8), acc);
                qe[nt] = mfma16(aq1, *reinterpret_cast<const short8*>(erow + 32 + g * 8), acc);
            }
            #pragma unroll
            for (int j = 0; j < 4; ++j) {
                float sh[5];
                #pragma unroll
                for (int q5 = 0; q5 < 5; ++q5) sh[q5] = __shfl(qe[q5][j], srcl[j]);
                const int lr = g * 4 + j;
                #pragma unroll
                for (int nt = 0; nt < 4; ++nt) {
                    const float rel = condj[j] ? sh[nt + 1] : sh[nt];
                    const int ki = nt * 16 + n15;
                    float v = (sl[nt][j] + rel) * 0.125f;
                    v = fminf(v, 60.f);
                    lsum[j] += (k0 + ki <= l0 + lr) ? __expf(v) : 0.f;
                }
            }
        }
        #pragma unroll
        for (int j = 0; j < 4; ++j) {
            float s2 = lsum[j];
            #pragma unroll
            for (int off = 1; off < 16; off <<= 1) s2 += __shfl_xor(s2, off);
            if (n15 == 0) lsum_s[w * 16 + g * 4 + j] = s2;
        }
        __syncthreads();
        if (tid < 16) {
            float acc = 0.f;
            #pragma unroll
            for (int w2 = 0; w2 < 8; ++w2) acc += lsum_s[w2 * 16 + tid];
            linvg[bh * kS + l0 + tid] = 1.f / acc;
        }
        __syncthreads();                         // lsum_s reuse in next phase
    }
}

// ---------------------------------------------------------------------------
// Attention kernel B: emit normalized probs + zero-fill + PV + O write.
// Same (bh, pair) blocking; wave w takes slots t = w, w+8, w+16, w+24 of 32
// (active or zero-fill) -> exactly 4 slots/wave/phase, uniform.
// LDS: Ps = smem[0,16K) (8 waves x 2KB, swizzled); O_s = smem[0,32K) after.
// ---------------------------------------------------------------------------
__global__ __launch_bounds__(512, 8)
void attn_emit_kernel(const ushort* __restrict__ qh, const ushort* __restrict__ kh,
                      const ushort* __restrict__ vt, const ushort* __restrict__ eb,
                      const float* __restrict__ linvg,
                      float* __restrict__ attn, ushort* __restrict__ ohb)
{
    __shared__ __align__(16) char smem[32768];

    const int bh   = blockIdx.x;
    const int p    = blockIdx.y;
    const int tid  = threadIdx.x;
    const int w    = tid >> 6;
    const int lane = tid & 63;
    const int g    = lane >> 4;
    const int n15  = lane & 15;
    const size_t bhS = (size_t)bh * kS;

    char* PsB = smem + w * 2048;                 // wave-private 16x64 bf16
    const int swr = (n15 & 7) << 4;

    int  srcl[4];
    bool condj[4];
    #pragma unroll
    for (int j = 0; j < 4; ++j) {
        const int d = n15 + 15 - (g * 4 + j);
        srcl[j]  = (lane & 48) | (d & 15);
        condj[j] = (d >= 16);
    }

    #pragma unroll
    for (int ph = 0; ph < 2; ++ph) {
        const int s  = ph ? (127 - p) : p;
        const int l0 = s * 16;
        const int T  = (s >> 2) + 1;

        const ushort* qrow = qh + (bhS + l0 + n15) * kDH;
        const short8 aq0 = *reinterpret_cast<const short8*>(qrow + g * 8);
        const short8 aq1 = *reinterpret_cast<const short8*>(qrow + 32 + g * 8);

        float linv[4];
        #pragma unroll
        for (int j = 0; j < 4; ++j) linv[j] = linvg[bh * kS + l0 + g * 4 + j];

        f32x4 o[4];
        #pragma unroll
        for (int nt = 0; nt < 4; ++nt) o[nt] = (f32x4){0.f, 0.f, 0.f, 0.f};

        for (int t = w; t < 32; t += 8) {
            const int k0 = t * 64;
            if (t >= T) {                        // fully masked: stream zeros
                const float4 z = make_float4(0.f, 0.f, 0.f, 0.f);
                #pragma unroll
                for (int rr = 0; rr < 4; ++rr) {
                    const int row = rr * 4 + g;
                    *reinterpret_cast<float4*>(attn + (bhS + l0 + row) * kS + k0 + n15 * 4) = z;
                }
                continue;
            }
            float sl[4][4];
            #pragma unroll
            for (int nt = 0; nt < 4; ++nt) {
                const ushort* krow = kh + (bhS + k0 + nt * 16 + n15) * kDH;
                f32x4 acc = {0.f, 0.f, 0.f, 0.f};
                acc = mfma16(aq0, *reinterpret_cast<const short8*>(krow + g * 8), acc);
                acc = mfma16(aq1, *reinterpret_cast<const short8*>(krow + 32 + g * 8), acc);
                #pragma unroll
                for (int j = 0; j < 4; ++j) sl[nt][j] = acc[j];
            }
            const int m_lo = 2032 + k0 - l0;
            f32x4 qe[5];
            #pragma unroll
            for (int nt = 0; nt < 5; ++nt) {
                int er = m_lo + nt * 16 + n15;
                if (er > kS - 1) er = kS - 1;
                const ushort* erow = eb + (size_t)er * kDH;
                f32x4 acc = {0.f, 0.f, 0.f, 0.f};
                acc = mfma16(aq0, *reinterpret_cast<const short8*>(erow + g * 8), acc);
                qe[nt] = mfma16(aq1, *reinterpret_cast<const short8*>(erow + 32 + g * 8), acc);
            }
            #pragma unroll
            for (int j = 0; j < 4; ++j) {
                float sh[5];
                #pragma unroll
                for (int q5 = 0; q5 < 5; ++q5) sh[q5] = __shfl(qe[q5][j], srcl[j]);
                const int lr = g * 4 + j;
                const int swl = (lr & 7) << 4;
                #pragma unroll
                for (int nt = 0; nt < 4; ++nt) {
                    const float rel = condj[j] ? sh[nt + 1] : sh[nt];
                    const int ki = nt * 16 + n15;
                    float v = (sl[nt][j] + rel) * 0.125f;
                    v = fminf(v, 60.f);
                    const float pe = (k0 + ki <= l0 + lr) ? __expf(v) * linv[j] : 0.f;
                    attn[(bhS + l0 + lr) * kS + k0 + ki] = pe;
                    const int byte = lr * 128 + ((((ki >> 3) << 4) ^ swl) | ((ki & 7) * 2));
                    *(__hip_bfloat16*)(PsB + byte) = __float2bfloat16(pe);
                }
            }
            WAVE_LDS_FENCE();                    // Ps writes -> reads
            const short8 pa0 = *reinterpret_cast<const short8*>(PsB + n15 * 128 + (((0 + g) << 4) ^ swr));
            const short8 pa1 = *reinterpret_cast<const short8*>(PsB + n15 * 128 + (((4 + g) << 4) ^ swr));
            WAVE_LDS_FENCE();                    // Ps reads -> next tile's writes (WAR)
            #pragma unroll
            for (int nt = 0; nt < 4; ++nt) {
                const ushort* vrow = vt + ((size_t)bh * kDH + nt * 16 + n15) * kS + k0;
                o[nt] = mfma16(pa0, *reinterpret_cast<const short8*>(vrow + g * 8), o[nt]);
                o[nt] = mfma16(pa1, *reinterpret_cast<const short8*>(vrow + 32 + g * 8), o[nt]);
            }
        }

        // O combine across 8 waves (O_s aliases Ps region)
        __syncthreads();                         // all waves done with Ps
        float* O_s = (float*)smem;               // 8 x 16 x 64 f32 = 32 KiB
        #pragma unroll
        for (int nt = 0; nt < 4; ++nt)
            #pragma unroll
            for (int j = 0; j < 4; ++j)
                O_s[w * 1024 + (g * 4 + j) * 64 + nt * 16 + n15] = o[nt][j];
        __syncthreads();

        const int b = bh >> 3, h = bh & 7;
        #pragma unroll
        for (int i = tid; i < 1024; i += 512) {
            const int r = i >> 6, c = i & 63;
            float acc = 0.f;
            #pragma unroll
            for (int w2 = 0; w2 < 8; ++w2) acc += O_s[w2 * 1024 + i];
            ohb[((size_t)b * kS + l0 + r) * kD + h * kDH + c] = (ushort)bfbits(acc);
        }
        __syncthreads();                         // O_s/Ps reuse in next phase
    }
}

// ---------------------------------------------------------------------------
extern "C" void kernel_launch(void* const* d_in, const int* in_sizes, int n_in,
                              void* d_out, int out_size, void* d_ws, size_t ws_size,
                              hipStream_t stream)
{
    const float* q_in = (const float*)d_in[0];
    const float* k_in = (const float*)d_in[1];
    const float* v_in = (const float*)d_in[2];
    const float* Wq = (const float*)d_in[4];
    const float* bq = (const float*)d_in[5];
    const float* Wk = (const float*)d_in[6];
    const float* bk = (const float*)d_in[7];
    const float* Wv = (const float*)d_in[8];
    const float* bv = (const float*)d_in[9];
    const float* Wo = (const float*)d_in[10];
    const float* bo = (const float*)d_in[11];
    const float* E  = (const float*)d_in[12];

    float* out  = (float*)d_out;                          // (B,S,D)
    float* attn = (float*)d_out + (size_t)kB * kS * kD;   // (B,H,S,S)

    // workspace: bf16 buffers + linvg (~32 MB)
    ushort* qh  = (ushort*)d_ws;          // (B,H,S,DH)
    ushort* kh  = qh  + 2097152;          // (B,H,S,DH)
    ushort* vt  = kh  + 2097152;          // (B,H,DH,S)
    ushort* ohb = vt  + 2097152;          // (B,S,D)
    ushort* qb  = ohb + 2097152;          // (B,S,D) inputs in bf16
    ushort* kb  = qb  + 2097152;
    ushort* vb  = kb  + 2097152;
    ushort* eb  = vb  + 2097152;          // (2048,64)
    ushort* Wqt = eb  + 131072;           // col-major 512x512
    ushort* Wkt = Wqt + 262144;
    ushort* Wvt = Wkt + 262144;
    ushort* Wot = Wvt + 262144;
    float*  linvg = (float*)(Wot + 262144);   // (16,2048)

    convw_kernel<<<dim3(8, 8, 5), 256, 0, stream>>>(Wq, Wk, Wv, Wo, E,
                                                    Wqt, Wkt, Wvt, Wot, eb);
    cvta_kernel<<<dim3(1024, 1, 3), 256, 0, stream>>>(q_in, k_in, v_in, qb, kb, vb);
    gemm_qkv_kernel<<<dim3(64, 16, 3), 256, 0, stream>>>(qb, kb, vb,
                                                         Wqt, Wkt, Wvt,
                                                         bq, bk, bv, qh, kh, vt);
    attn_lsum_kernel<<<dim3(16, 64), 512, 0, stream>>>(qh, kh, eb, linvg);
    attn_emit_kernel<<<dim3(16, 64), 512, 0, stream>>>(qh, kh, vt, eb, linvg, attn, ohb);
    gemm_o_kernel<<<dim3(64, 16), 256, 0, stream>>>(ohb, Wot, bo, out);
}

// Round 9
// 292.015 us; speedup vs baseline: 2.1027x; 2.1027x over previous
//
#include <hip/hip_runtime.h>
#include <hip/hip_bf16.h>

// RelativeGlobalAttention: B=2, S=2048, D=512, H=8, DH=64, MAX_SEQ=2048
// out0 = attention output (B,S,D); out1 = attn probs (B,H,S,S); concatenated in d_out.
//
// Identity: srel[l,k] = q[l].E[2047-l+k] for k<=l, else 0.
// logits = (QK^T + srel)/8; causal mask => masked probs exactly 0.
// No-max softmax: exp(v)/sum(exp(v)) == reference softmax up to fp32 rounding.
//
// R9 = R8 with the compile fix: __builtin_nontemporal_store needs a clang
// ext-vector pointer, not HIP's float4 class. Theory unchanged: nt stores
// keep the 268MB attn stream from evicting K/V/E (2.25MB/XCD) out of L2.

namespace {
constexpr int kS  = 2048;
constexpr int kD  = 512;
constexpr int kH  = 8;
constexpr int kDH = 64;
constexpr int kB  = 2;

typedef __attribute__((ext_vector_type(8))) short short8;   // 8 x bf16
typedef __attribute__((ext_vector_type(4))) float f32x4;
}

// compiler fence for wave-private LDS write->read ordering (same-wave DS ops
// execute in order in HW; this stops compiler reordering, R4's failure mode).
#define WAVE_LDS_FENCE() do { \
    asm volatile("s_waitcnt lgkmcnt(0)" ::: "memory"); \
    __builtin_amdgcn_sched_barrier(0); \
} while (0)

__device__ __forceinline__ f32x4 mfma16(short8 a, short8 b, f32x4 c) {
    return __builtin_amdgcn_mfma_f32_16x16x32_bf16(a, b, c, 0, 0, 0);
}

__device__ __forceinline__ short bfbits(float f) {
    __hip_bfloat16 h = __float2bfloat16(f);
    return *reinterpret_cast<short*>(&h);
}

// ---------------------------------------------------------------------------
// conv: W (512x512 fp32 row-major) -> Wt (bf16 col-major [c][k]) x4; E -> bf16
// ---------------------------------------------------------------------------
__global__ __launch_bounds__(256)
void convw_kernel(const float* __restrict__ Wq, const float* __restrict__ Wk,
                  const float* __restrict__ Wv, const float* __restrict__ Wo,
                  const float* __restrict__ E,
                  ushort* __restrict__ Wqt, ushort* __restrict__ Wkt,
                  ushort* __restrict__ Wvt, ushort* __restrict__ Wot,
                  ushort* __restrict__ eb)
{
    const int z = blockIdx.z;
    const int tid = threadIdx.x;
    if (z == 4) {   // E: 2048x64 = 131072 elems
        const int idx = ((blockIdx.y * 8 + blockIdx.x) * 256 + tid) * 8;
        const float4 x = *reinterpret_cast<const float4*>(E + idx);
        const float4 y = *reinterpret_cast<const float4*>(E + idx + 4);
        short8 r;
        r[0] = bfbits(x.x); r[1] = bfbits(x.y); r[2] = bfbits(x.z); r[3] = bfbits(x.w);
        r[4] = bfbits(y.x); r[5] = bfbits(y.y); r[6] = bfbits(y.z); r[7] = bfbits(y.w);
        *reinterpret_cast<short8*>(eb + idx) = r;
        return;
    }
    const float* W = (z == 0) ? Wq : (z == 1) ? Wk : (z == 2) ? Wv : Wo;
    ushort* Wt = (z == 0) ? Wqt : (z == 1) ? Wkt : (z == 2) ? Wvt : Wot;

    __shared__ float Ws[64][65];
    const int k0 = blockIdx.x * 64;
    const int c0 = blockIdx.y * 64;
    const int cc = tid & 63;
    const int rq = tid >> 6;
    #pragma unroll
    for (int ii = 0; ii < 16; ++ii) {
        const int r = ii * 4 + rq;
        Ws[r][cc] = W[(size_t)(k0 + r) * kD + c0 + cc];
    }
    __syncthreads();
    #pragma unroll
    for (int ii = 0; ii < 16; ++ii) {
        const int r = ii * 4 + rq;
        Wt[(size_t)(c0 + r) * kD + k0 + cc] = (ushort)bfbits(Ws[cc][r]);
    }
}

// q_in/k_in/v_in fp32 (B,S,D) -> bf16
__global__ __launch_bounds__(256)
void cvta_kernel(const float* __restrict__ q, const float* __restrict__ k,
                 const float* __restrict__ v,
                 ushort* __restrict__ qb, ushort* __restrict__ kb,
                 ushort* __restrict__ vb)
{
    const int z = blockIdx.z;
    const float* src = (z == 0) ? q : (z == 1) ? k : v;
    ushort* dst = (z == 0) ? qb : (z == 1) ? kb : vb;
    const int idx = (blockIdx.x * 256 + threadIdx.x) * 8;
    const float4 x = *reinterpret_cast<const float4*>(src + idx);
    const float4 y = *reinterpret_cast<const float4*>(src + idx + 4);
    short8 r;
    r[0] = bfbits(x.x); r[1] = bfbits(x.y); r[2] = bfbits(x.z); r[3] = bfbits(x.w);
    r[4] = bfbits(y.x); r[5] = bfbits(y.y); r[6] = bfbits(y.z); r[7] = bfbits(y.w);
    *reinterpret_cast<short8*>(dst + idx) = r;
}

// ---------------------------------------------------------------------------
// MFMA GEMM core (unchanged)
// ---------------------------------------------------------------------------
template<int MODE>
__device__ __forceinline__
void gemm_core(const ushort* __restrict__ A, const ushort* __restrict__ Wt,
               const float* __restrict__ bias, void* __restrict__ out)
{
    const int tid  = threadIdx.x;
    const int w    = tid >> 6;
    const int lane = tid & 63;
    const int g    = lane >> 4;
    const int n15  = lane & 15;
    const int r0   = blockIdx.x * 64 + w * 16;
    const int c0   = blockIdx.y * 32;

    f32x4 acc0 = {0.f, 0.f, 0.f, 0.f};
    f32x4 acc1 = {0.f, 0.f, 0.f, 0.f};
    const ushort* arow = A  + (size_t)(r0 + n15) * kD + g * 8;
    const ushort* b0p  = Wt + (size_t)(c0 + n15) * kD + g * 8;
    const ushort* b1p  = Wt + (size_t)(c0 + 16 + n15) * kD + g * 8;

    #pragma unroll 4
    for (int k0 = 0; k0 < kD; k0 += 32) {
        const short8 a  = *reinterpret_cast<const short8*>(arow + k0);
        const short8 b0 = *reinterpret_cast<const short8*>(b0p + k0);
        const short8 b1 = *reinterpret_cast<const short8*>(b1p + k0);
        acc0 = mfma16(a, b0, acc0);
        acc1 = mfma16(a, b1, acc1);
    }

    #pragma unroll
    for (int cg = 0; cg < 2; ++cg) {
        const f32x4 acc = cg ? acc1 : acc0;
        const int c = c0 + cg * 16 + n15;
        const float bb = bias[c];
        const int h = c >> 6, d = c & (kDH - 1);
        #pragma unroll
        for (int j = 0; j < 4; ++j) {
            const int r = r0 + g * 4 + j;
            const float val = acc[j] + bb;
            const int b = r >> 11, s2 = r & (kS - 1);
            if (MODE == 0) {
                ((float*)out)[(size_t)r * kD + c] = val;
            } else if (MODE == 1) {
                ((ushort*)out)[((size_t)(b * kH + h) * kS + s2) * kDH + d] = (ushort)bfbits(val);
            } else {
                ((ushort*)out)[((size_t)(b * kH + h) * kDH + d) * kS + s2] = (ushort)bfbits(val);
            }
        }
    }
}

__global__ __launch_bounds__(256)
void gemm_qkv_kernel(const ushort* __restrict__ qb, const ushort* __restrict__ kb,
                     const ushort* __restrict__ vb,
                     const ushort* __restrict__ Wqt, const ushort* __restrict__ Wkt,
                     const ushort* __restrict__ Wvt,
                     const float* __restrict__ bq, const float* __restrict__ bk,
                     const float* __restrict__ bv,
                     ushort* __restrict__ qh, ushort* __restrict__ kh,
                     ushort* __restrict__ vt)
{
    const int z = blockIdx.z;
    const ushort* A    = (z == 0) ? qb  : (z == 1) ? kb  : vb;
    const ushort* Wt   = (z == 0) ? Wqt : (z == 1) ? Wkt : Wvt;
    const float*  bias = (z == 0) ? bq  : (z == 1) ? bk  : bv;
    void*         out  = (z == 0) ? (void*)qh : (z == 1) ? (void*)kh : (void*)vt;
    if (z == 2) gemm_core<2>(A, Wt, bias, out);
    else        gemm_core<1>(A, Wt, bias, out);
}

__global__ __launch_bounds__(256)
void gemm_o_kernel(const ushort* __restrict__ ohb, const ushort* __restrict__ Wot,
                   const float* __restrict__ bo, float* __restrict__ out)
{
    gemm_core<0>(ohb, Wot, bo, out);
}

// ---------------------------------------------------------------------------
// Fused attention (R6 structure). Block = (bh, 16-row strip) x 4 waves;
// wave w owns tiles t = w, w+4, ... Rel scores via in-register shfl diagonal
// gather. Ps transpose in wave-private LDS + lgkmcnt fences. 3 block barriers.
// attn stores are NON-TEMPORAL (keep K/V/E resident in per-XCD L2).
// grid (16, 128) x 256. Default block->XCD map gives XCD = bh % 8.
// ---------------------------------------------------------------------------
__global__ __launch_bounds__(256, 4)
void attn_fused_kernel(const ushort* __restrict__ qh, const ushort* __restrict__ kh,
                       const ushort* __restrict__ vt, const ushort* __restrict__ eb,
                       float* __restrict__ attn, ushort* __restrict__ ohb)
{
    // LDS: [0,8192) Ps (4 waves x 16x64 bf16, swizzled)  -- aliased by O_s
    //      [16384,16640) lsum_s ; O_s = [0,16384) after pass B
    __shared__ __align__(16) char smem[16640];

    const int bh    = blockIdx.x;
    const int strip = 127 - (int)blockIdx.y;     // big-work-first
    const int l0    = strip * 16;
    const int tid   = threadIdx.x;
    const int w     = tid >> 6;
    const int lane  = tid & 63;
    const int g     = lane >> 4;
    const int n15   = lane & 15;
    const size_t bhS = (size_t)bh * kS;

    char*  PsB = smem + w * 2048;                // 16x64 bf16 swizzled
    float* lsum_s = (float*)(smem + 16384);

    const int T = ((l0 + 15) >> 6) + 1;          // causal 64-wide tiles

    const ushort* qrow = qh + (bhS + l0 + n15) * kDH;
    const short8 aq0 = *reinterpret_cast<const short8*>(qrow + g * 8);
    const short8 aq1 = *reinterpret_cast<const short8*>(qrow + 32 + g * 8);

    // diagonal-gather constants: R[lr][ki] = qe[lr][ki-lr+15] lives at
    // col-lane (d&15), register nt + (d>=16), d = n15 + 15 - lr.
    int  srcl[4];
    bool condj[4];
    #pragma unroll
    for (int j = 0; j < 4; ++j) {
        const int d = n15 + 15 - (g * 4 + j);
        srcl[j]  = (lane & 48) | (d & 15);
        condj[j] = (d >= 16);
    }

    // ---------------- pass A: row sums (no barriers) ----------------
    float lsum[4] = {0.f, 0.f, 0.f, 0.f};
    for (int t = w; t < T; t += 4) {
        const int k0 = t * 64;
        float sl[4][4];
        #pragma unroll
        for (int nt = 0; nt < 4; ++nt) {
            const ushort* krow = kh + (bhS + k0 + nt * 16 + n15) * kDH;
            f32x4 acc = {0.f, 0.f, 0.f, 0.f};
            acc = mfma16(aq0, *reinterpret_cast<const short8*>(krow + g * 8), acc);
            acc = mfma16(aq1, *reinterpret_cast<const short8*>(krow + 32 + g * 8), acc);
            #pragma unroll
            for (int j = 0; j < 4; ++j) sl[nt][j] = acc[j];
        }
        const int m_lo = 2032 + k0 - l0;
        f32x4 qe[5];
        #pragma unroll
        for (int nt = 0; nt < 5; ++nt) {
            int er = m_lo + nt * 16 + n15;
            if (er > kS - 1) er = kS - 1;        // clamped rows only feed masked elems
            const ushort* erow = eb + (size_t)er * kDH;
            f32x4 acc = {0.f, 0.f, 0.f, 0.f};
            acc = mfma16(aq0, *reinterpret_cast<const short8*>(erow + g * 8), acc);
            qe[nt] = mfma16(aq1, *reinterpret_cast<const short8*>(erow + 32 + g * 8), acc);
        }
        #pragma unroll
        for (int j = 0; j < 4; ++j) {
            float sh[5];
            #pragma unroll
            for (int q5 = 0; q5 < 5; ++q5) sh[q5] = __shfl(qe[q5][j], srcl[j]);
            const int lr = g * 4 + j;
            #pragma unroll
            for (int nt = 0; nt < 4; ++nt) {
                const float rel = condj[j] ? sh[nt + 1] : sh[nt];
                const int ki = nt * 16 + n15;
                float v = (sl[nt][j] + rel) * 0.125f;
                v = fminf(v, 60.f);
                lsum[j] += (k0 + ki <= l0 + lr) ? __expf(v) : 0.f;
            }
        }
    }
    #pragma unroll
    for (int j = 0; j < 4; ++j) {
        float s = lsum[j];
        #pragma unroll
        for (int off = 1; off < 16; off <<= 1) s += __shfl_xor(s, off);
        if (n15 == 0) lsum_s[w * 16 + g * 4 + j] = s;
    }
    __syncthreads();                             // [barrier 1] lsum exchange

    float linv[4];
    #pragma unroll
    for (int j = 0; j < 4; ++j) {
        const int r = g * 4 + j;
        linv[j] = 1.f / (lsum_s[r] + lsum_s[16 + r] + lsum_s[32 + r] + lsum_s[48 + r]);
    }

    // ---------------- pass B: emit + PV (wave-local fences only) ----------------
    f32x4 o[4];
    #pragma unroll
    for (int nt = 0; nt < 4; ++nt) o[nt] = (f32x4){0.f, 0.f, 0.f, 0.f};
    const int swr = (n15 & 7) << 4;

    for (int t = w; t < 32; t += 4) {
        const int k0 = t * 64;
        if (t >= T) {                            // fully masked: stream zeros (nt)
            const f32x4 z = {0.f, 0.f, 0.f, 0.f};
            #pragma unroll
            for (int rr = 0; rr < 4; ++rr) {
                const int row = rr * 4 + g;
                __builtin_nontemporal_store(
                    z, reinterpret_cast<f32x4*>(attn + (bhS + l0 + row) * kS + k0 + n15 * 4));
            }
            continue;
        }
        float sl[4][4];
        #pragma unroll
        for (int nt = 0; nt < 4; ++nt) {
            const ushort* krow = kh + (bhS + k0 + nt * 16 + n15) * kDH;
            f32x4 acc = {0.f, 0.f, 0.f, 0.f};
            acc = mfma16(aq0, *reinterpret_cast<const short8*>(krow + g * 8), acc);
            acc = mfma16(aq1, *reinterpret_cast<const short8*>(krow + 32 + g * 8), acc);
            #pragma unroll
            for (int j = 0; j < 4; ++j) sl[nt][j] = acc[j];
        }
        const int m_lo = 2032 + k0 - l0;
        f32x4 qe[5];
        #pragma unroll
        for (int nt = 0; nt < 5; ++nt) {
            int er = m_lo + nt * 16 + n15;
            if (er > kS - 1) er = kS - 1;
            const ushort* erow = eb + (size_t)er * kDH;
            f32x4 acc = {0.f, 0.f, 0.f, 0.f};
            acc = mfma16(aq0, *reinterpret_cast<const short8*>(erow + g * 8), acc);
            qe[nt] = mfma16(aq1, *reinterpret_cast<const short8*>(erow + 32 + g * 8), acc);
        }
        #pragma unroll
        for (int j = 0; j < 4; ++j) {
            float sh[5];
            #pragma unroll
            for (int q5 = 0; q5 < 5; ++q5) sh[q5] = __shfl(qe[q5][j], srcl[j]);
            const int lr = g * 4 + j;
            const int swl = (lr & 7) << 4;
            #pragma unroll
            for (int nt = 0; nt < 4; ++nt) {
                const float rel = condj[j] ? sh[nt + 1] : sh[nt];
                const int ki = nt * 16 + n15;
                float v = (sl[nt][j] + rel) * 0.125f;
                v = fminf(v, 60.f);
                const float pe = (k0 + ki <= l0 + lr) ? __expf(v) * linv[j] : 0.f;
                __builtin_nontemporal_store(pe, attn + (bhS + l0 + lr) * kS + k0 + ki);
                const int byte = lr * 128 + ((((ki >> 3) << 4) ^ swl) | ((ki & 7) * 2));
                *(__hip_bfloat16*)(PsB + byte) = __float2bfloat16(pe);
            }
        }
        WAVE_LDS_FENCE();                        // Ps writes -> reads
        const short8 pa0 = *reinterpret_cast<const short8*>(PsB + n15 * 128 + (((0 + g) << 4) ^ swr));
        const short8 pa1 = *reinterpret_cast<const short8*>(PsB + n15 * 128 + (((4 + g) << 4) ^ swr));
        WAVE_LDS_FENCE();                        // Ps reads retired (WAR vs next tile)
        #pragma unroll
        for (int nt = 0; nt < 4; ++nt) {
            const ushort* vrow = vt + ((size_t)bh * kDH + nt * 16 + n15) * kS + k0;
            o[nt] = mfma16(pa0, *reinterpret_cast<const short8*>(vrow + g * 8), o[nt]);
            o[nt] = mfma16(pa1, *reinterpret_cast<const short8*>(vrow + 32 + g * 8), o[nt]);
        }
    }

    // ---------------- O combine (O_s aliases Ps region) ----------------
    __syncthreads();                             // [barrier 2] all Ps reads done
    float* O_s = (float*)smem;                   // 4 waves x 16x64 f32 = 16 KiB
    #pragma unroll
    for (int nt = 0; nt < 4; ++nt)
        #pragma unroll
        for (int j = 0; j < 4; ++j)
            O_s[w * 1024 + (g * 4 + j) * 64 + nt * 16 + n15] = o[nt][j];
    __syncthreads();                             // [barrier 3]

    const int b = bh >> 3, h = bh & 7;
    #pragma unroll
    for (int i = tid; i < 1024; i += 256) {
        const int r = i >> 6, c = i & 63;
        const float acc = O_s[i] + O_s[1024 + i] + O_s[2048 + i] + O_s[3072 + i];
        ohb[((size_t)b * kS + l0 + r) * kD + h * kDH + c] = (ushort)bfbits(acc);
    }
}

// ---------------------------------------------------------------------------
extern "C" void kernel_launch(void* const* d_in, const int* in_sizes, int n_in,
                              void* d_out, int out_size, void* d_ws, size_t ws_size,
                              hipStream_t stream)
{
    const float* q_in = (const float*)d_in[0];
    const float* k_in = (const float*)d_in[1];
    const float* v_in = (const float*)d_in[2];
    const float* Wq = (const float*)d_in[4];
    const float* bq = (const float*)d_in[5];
    const float* Wk = (const float*)d_in[6];
    const float* bk = (const float*)d_in[7];
    const float* Wv = (const float*)d_in[8];
    const float* bv = (const float*)d_in[9];
    const float* Wo = (const float*)d_in[10];
    const float* bo = (const float*)d_in[11];
    const float* E  = (const float*)d_in[12];

    float* out  = (float*)d_out;                          // (B,S,D)
    float* attn = (float*)d_out + (size_t)kB * kS * kD;   // (B,H,S,S)

    // workspace: all bf16 (~31.7 MB)
    ushort* qh  = (ushort*)d_ws;          // (B,H,S,DH)
    ushort* kh  = qh  + 2097152;          // (B,H,S,DH)
    ushort* vt  = kh  + 2097152;          // (B,H,DH,S)
    ushort* ohb = vt  + 2097152;          // (B,S,D)
    ushort* qb  = ohb + 2097152;          // (B,S,D) inputs in bf16
    ushort* kb  = qb  + 2097152;
    ushort* vb  = kb  + 2097152;
    ushort* eb  = vb  + 2097152;          // (2048,64)
    ushort* Wqt = eb  + 131072;           // col-major 512x512
    ushort* Wkt = Wqt + 262144;
    ushort* Wvt = Wkt + 262144;
    ushort* Wot = Wvt + 262144;

    convw_kernel<<<dim3(8, 8, 5), 256, 0, stream>>>(Wq, Wk, Wv, Wo, E,
                                                    Wqt, Wkt, Wvt, Wot, eb);
    cvta_kernel<<<dim3(1024, 1, 3), 256, 0, stream>>>(q_in, k_in, v_in, qb, kb, vb);
    gemm_qkv_kernel<<<dim3(64, 16, 3), 256, 0, stream>>>(qb, kb, vb,
                                                         Wqt, Wkt, Wvt,
                                                         bq, bk, bv, qh, kh, vt);
    attn_fused_kernel<<<dim3(16, 128), 256, 0, stream>>>(qh, kh, vt, eb, attn, ohb);
    gemm_o_kernel<<<dim3(64, 16), 256, 0, stream>>>(ohb, Wot, bo, out);
}

// Round 10
// 287.255 us; speedup vs baseline: 2.1375x; 1.0166x over previous
//
#include <hip/hip_runtime.h>
#include <hip/hip_bf16.h>

// RelativeGlobalAttention: B=2, S=2048, D=512, H=8, DH=64, MAX_SEQ=2048
// out0 = attention output (B,S,D); out1 = attn probs (B,H,S,S); concatenated in d_out.
//
// Identity: srel[l,k] = q[l].E[2047-l+k] for k<=l, else 0.
// logits = (QK^T + srel)/8; causal mask => masked probs exactly 0.
// No-max softmax: exp(v)/sum(exp(v)) == reference softmax up to fp32 rounding.
//
// R10 theory: effective store throughput (~1.5 TB/s) is the wall -- all attn
// stores were 64B segments (scalar fp32 x 16 lanes/row; f32x4 zerofill = 4
// lanes/row). Harness memsets on the same buffer run 6.9 TB/s with contiguous
// 256B/wave. Fix: stage pe in a wave-private fp32 LDS tile [16][68], read
// back row-major (lanes 0..15 = one row) -> 4 store instrs/tile, 256B
// contiguous per row segment. Same tile feeds PV A-frags (f32->bf16 pack),
// replacing the bf16 Ps path bit-identically.

namespace {
constexpr int kS  = 2048;
constexpr int kD  = 512;
constexpr int kH  = 8;
constexpr int kDH = 64;
constexpr int kB  = 2;

typedef __attribute__((ext_vector_type(8))) short short8;   // 8 x bf16
typedef __attribute__((ext_vector_type(4))) float f32x4;
}

// compiler fence for wave-private LDS write->read ordering (same-wave DS ops
// execute in order in HW; this stops compiler reordering, R4's failure mode).
#define WAVE_LDS_FENCE() do { \
    asm volatile("s_waitcnt lgkmcnt(0)" ::: "memory"); \
    __builtin_amdgcn_sched_barrier(0); \
} while (0)

__device__ __forceinline__ f32x4 mfma16(short8 a, short8 b, f32x4 c) {
    return __builtin_amdgcn_mfma_f32_16x16x32_bf16(a, b, c, 0, 0, 0);
}

__device__ __forceinline__ short bfbits(float f) {
    __hip_bfloat16 h = __float2bfloat16(f);
    return *reinterpret_cast<short*>(&h);
}

// ---------------------------------------------------------------------------
// conv: W (512x512 fp32 row-major) -> Wt (bf16 col-major [c][k]) x4; E -> bf16
// ---------------------------------------------------------------------------
__global__ __launch_bounds__(256)
void convw_kernel(const float* __restrict__ Wq, const float* __restrict__ Wk,
                  const float* __restrict__ Wv, const float* __restrict__ Wo,
                  const float* __restrict__ E,
                  ushort* __restrict__ Wqt, ushort* __restrict__ Wkt,
                  ushort* __restrict__ Wvt, ushort* __restrict__ Wot,
                  ushort* __restrict__ eb)
{
    const int z = blockIdx.z;
    const int tid = threadIdx.x;
    if (z == 4) {   // E: 2048x64 = 131072 elems
        const int idx = ((blockIdx.y * 8 + blockIdx.x) * 256 + tid) * 8;
        const float4 x = *reinterpret_cast<const float4*>(E + idx);
        const float4 y = *reinterpret_cast<const float4*>(E + idx + 4);
        short8 r;
        r[0] = bfbits(x.x); r[1] = bfbits(x.y); r[2] = bfbits(x.z); r[3] = bfbits(x.w);
        r[4] = bfbits(y.x); r[5] = bfbits(y.y); r[6] = bfbits(y.z); r[7] = bfbits(y.w);
        *reinterpret_cast<short8*>(eb + idx) = r;
        return;
    }
    const float* W = (z == 0) ? Wq : (z == 1) ? Wk : (z == 2) ? Wv : Wo;
    ushort* Wt = (z == 0) ? Wqt : (z == 1) ? Wkt : (z == 2) ? Wvt : Wot;

    __shared__ float Ws[64][65];
    const int k0 = blockIdx.x * 64;
    const int c0 = blockIdx.y * 64;
    const int cc = tid & 63;
    const int rq = tid >> 6;
    #pragma unroll
    for (int ii = 0; ii < 16; ++ii) {
        const int r = ii * 4 + rq;
        Ws[r][cc] = W[(size_t)(k0 + r) * kD + c0 + cc];
    }
    __syncthreads();
    #pragma unroll
    for (int ii = 0; ii < 16; ++ii) {
        const int r = ii * 4 + rq;
        Wt[(size_t)(c0 + r) * kD + k0 + cc] = (ushort)bfbits(Ws[cc][r]);
    }
}

// q_in/k_in/v_in fp32 (B,S,D) -> bf16
__global__ __launch_bounds__(256)
void cvta_kernel(const float* __restrict__ q, const float* __restrict__ k,
                 const float* __restrict__ v,
                 ushort* __restrict__ qb, ushort* __restrict__ kb,
                 ushort* __restrict__ vb)
{
    const int z = blockIdx.z;
    const float* src = (z == 0) ? q : (z == 1) ? k : v;
    ushort* dst = (z == 0) ? qb : (z == 1) ? kb : vb;
    const int idx = (blockIdx.x * 256 + threadIdx.x) * 8;
    const float4 x = *reinterpret_cast<const float4*>(src + idx);
    const float4 y = *reinterpret_cast<const float4*>(src + idx + 4);
    short8 r;
    r[0] = bfbits(x.x); r[1] = bfbits(x.y); r[2] = bfbits(x.z); r[3] = bfbits(x.w);
    r[4] = bfbits(y.x); r[5] = bfbits(y.y); r[6] = bfbits(y.z); r[7] = bfbits(y.w);
    *reinterpret_cast<short8*>(dst + idx) = r;
}

// ---------------------------------------------------------------------------
// MFMA GEMM core (unchanged)
// ---------------------------------------------------------------------------
template<int MODE>
__device__ __forceinline__
void gemm_core(const ushort* __restrict__ A, const ushort* __restrict__ Wt,
               const float* __restrict__ bias, void* __restrict__ out)
{
    const int tid  = threadIdx.x;
    const int w    = tid >> 6;
    const int lane = tid & 63;
    const int g    = lane >> 4;
    const int n15  = lane & 15;
    const int r0   = blockIdx.x * 64 + w * 16;
    const int c0   = blockIdx.y * 32;

    f32x4 acc0 = {0.f, 0.f, 0.f, 0.f};
    f32x4 acc1 = {0.f, 0.f, 0.f, 0.f};
    const ushort* arow = A  + (size_t)(r0 + n15) * kD + g * 8;
    const ushort* b0p  = Wt + (size_t)(c0 + n15) * kD + g * 8;
    const ushort* b1p  = Wt + (size_t)(c0 + 16 + n15) * kD + g * 8;

    #pragma unroll 4
    for (int k0 = 0; k0 < kD; k0 += 32) {
        const short8 a  = *reinterpret_cast<const short8*>(arow + k0);
        const short8 b0 = *reinterpret_cast<const short8*>(b0p + k0);
        const short8 b1 = *reinterpret_cast<const short8*>(b1p + k0);
        acc0 = mfma16(a, b0, acc0);
        acc1 = mfma16(a, b1, acc1);
    }

    #pragma unroll
    for (int cg = 0; cg < 2; ++cg) {
        const f32x4 acc = cg ? acc1 : acc0;
        const int c = c0 + cg * 16 + n15;
        const float bb = bias[c];
        const int h = c >> 6, d = c & (kDH - 1);
        #pragma unroll
        for (int j = 0; j < 4; ++j) {
            const int r = r0 + g * 4 + j;
            const float val = acc[j] + bb;
            const int b = r >> 11, s2 = r & (kS - 1);
            if (MODE == 0) {
                ((float*)out)[(size_t)r * kD + c] = val;
            } else if (MODE == 1) {
                ((ushort*)out)[((size_t)(b * kH + h) * kS + s2) * kDH + d] = (ushort)bfbits(val);
            } else {
                ((ushort*)out)[((size_t)(b * kH + h) * kDH + d) * kS + s2] = (ushort)bfbits(val);
            }
        }
    }
}

__global__ __launch_bounds__(256)
void gemm_qkv_kernel(const ushort* __restrict__ qb, const ushort* __restrict__ kb,
                     const ushort* __restrict__ vb,
                     const ushort* __restrict__ Wqt, const ushort* __restrict__ Wkt,
                     const ushort* __restrict__ Wvt,
                     const float* __restrict__ bq, const float* __restrict__ bk,
                     const float* __restrict__ bv,
                     ushort* __restrict__ qh, ushort* __restrict__ kh,
                     ushort* __restrict__ vt)
{
    const int z = blockIdx.z;
    const ushort* A    = (z == 0) ? qb  : (z == 1) ? kb  : vb;
    const ushort* Wt   = (z == 0) ? Wqt : (z == 1) ? Wkt : Wvt;
    const float*  bias = (z == 0) ? bq  : (z == 1) ? bk  : bv;
    void*         out  = (z == 0) ? (void*)qh : (z == 1) ? (void*)kh : (void*)vt;
    if (z == 2) gemm_core<2>(A, Wt, bias, out);
    else        gemm_core<1>(A, Wt, bias, out);
}

__global__ __launch_bounds__(256)
void gemm_o_kernel(const ushort* __restrict__ ohb, const ushort* __restrict__ Wot,
                   const float* __restrict__ bo, float* __restrict__ out)
{
    gemm_core<0>(ohb, Wot, bo, out);
}

// ---------------------------------------------------------------------------
// Fused attention (R6 structure, R10 store path). Block = (bh, strip) x 4
// waves; wave w owns tiles t = w, w+4, ... Rel scores via in-register shfl
// diagonal gather. pe staged in wave-private fp32 LDS [16][68] ->
// (a) row-major f32x4 attn stores (256B/row segments, nontemporal),
// (b) PV A-frags (f32 -> bf16 pack). grid (16,128) x 256.
// ---------------------------------------------------------------------------
__global__ __launch_bounds__(256, 4)
void attn_fused_kernel(const ushort* __restrict__ qh, const ushort* __restrict__ kh,
                       const ushort* __restrict__ vt, const ushort* __restrict__ eb,
                       float* __restrict__ attn, ushort* __restrict__ ohb)
{
    // LDS: [0,17408) Pf32 (4 waves x 16x68 f32) -- aliased by O_s after pass B
    //      [17408,17664) lsum_s ; O_s = [0,16384)
    __shared__ __align__(16) char smem[17664];

    const int bh    = blockIdx.x;
    const int strip = 127 - (int)blockIdx.y;     // big-work-first
    const int l0    = strip * 16;
    const int tid   = threadIdx.x;
    const int w     = tid >> 6;
    const int lane  = tid & 63;
    const int g     = lane >> 4;
    const int n15   = lane & 15;
    const size_t bhS = (size_t)bh * kS;

    float* Pw = (float*)(smem + w * 4352);       // 16 x 68 f32, wave-private
    float* lsum_s = (float*)(smem + 17408);

    const int T = ((l0 + 15) >> 6) + 1;          // causal 64-wide tiles

    const ushort* qrow = qh + (bhS + l0 + n15) * kDH;
    const short8 aq0 = *reinterpret_cast<const short8*>(qrow + g * 8);
    const short8 aq1 = *reinterpret_cast<const short8*>(qrow + 32 + g * 8);

    // diagonal-gather constants: R[lr][ki] = qe[lr][ki-lr+15] lives at
    // col-lane (d&15), register nt + (d>=16), d = n15 + 15 - lr.
    int  srcl[4];
    bool condj[4];
    #pragma unroll
    for (int j = 0; j < 4; ++j) {
        const int d = n15 + 15 - (g * 4 + j);
        srcl[j]  = (lane & 48) | (d & 15);
        condj[j] = (d >= 16);
    }

    // ---------------- pass A: row sums (no barriers) ----------------
    float lsum[4] = {0.f, 0.f, 0.f, 0.f};
    for (int t = w; t < T; t += 4) {
        const int k0 = t * 64;
        float sl[4][4];
        #pragma unroll
        for (int nt = 0; nt < 4; ++nt) {
            const ushort* krow = kh + (bhS + k0 + nt * 16 + n15) * kDH;
            f32x4 acc = {0.f, 0.f, 0.f, 0.f};
            acc = mfma16(aq0, *reinterpret_cast<const short8*>(krow + g * 8), acc);
            acc = mfma16(aq1, *reinterpret_cast<const short8*>(krow + 32 + g * 8), acc);
            #pragma unroll
            for (int j = 0; j < 4; ++j) sl[nt][j] = acc[j];
        }
        const int m_lo = 2032 + k0 - l0;
        f32x4 qe[5];
        #pragma unroll
        for (int nt = 0; nt < 5; ++nt) {
            int er = m_lo + nt * 16 + n15;
            if (er > kS - 1) er = kS - 1;        // clamped rows only feed masked elems
            const ushort* erow = eb + (size_t)er * kDH;
            f32x4 acc = {0.f, 0.f, 0.f, 0.f};
            acc = mfma16(aq0, *reinterpret_cast<const short8*>(erow + g * 8), acc);
            qe[nt] = mfma16(aq1, *reinterpret_cast<const short8*>(erow + 32 + g * 8), acc);
        }
        #pragma unroll
        for (int j = 0; j < 4; ++j) {
            float sh[5];
            #pragma unroll
            for (int q5 = 0; q5 < 5; ++q5) sh[q5] = __shfl(qe[q5][j], srcl[j]);
            const int lr = g * 4 + j;
            #pragma unroll
            for (int nt = 0; nt < 4; ++nt) {
                const float rel = condj[j] ? sh[nt + 1] : sh[nt];
                const int ki = nt * 16 + n15;
                float v = (sl[nt][j] + rel) * 0.125f;
                v = fminf(v, 60.f);
                lsum[j] += (k0 + ki <= l0 + lr) ? __expf(v) : 0.f;
            }
        }
    }
    #pragma unroll
    for (int j = 0; j < 4; ++j) {
        float s = lsum[j];
        #pragma unroll
        for (int off = 1; off < 16; off <<= 1) s += __shfl_xor(s, off);
        if (n15 == 0) lsum_s[w * 16 + g * 4 + j] = s;
    }
    __syncthreads();                             // [barrier 1] lsum exchange

    float linv[4];
    #pragma unroll
    for (int j = 0; j < 4; ++j) {
        const int r = g * 4 + j;
        linv[j] = 1.f / (lsum_s[r] + lsum_s[16 + r] + lsum_s[32 + r] + lsum_s[48 + r]);
    }

    // ---------------- pass B: emit + PV (wave-local fences only) ----------------
    f32x4 o[4];
    #pragma unroll
    for (int nt = 0; nt < 4; ++nt) o[nt] = (f32x4){0.f, 0.f, 0.f, 0.f};

    const int rr4 = lane >> 4;                   // store-phase row in group
    const int cc4 = (lane & 15) * 4;             // store-phase col

    for (int t = w; t < 32; t += 4) {
        const int k0 = t * 64;
        if (t >= T) {                            // fully masked: 256B-segment zeros
            const f32x4 z = {0.f, 0.f, 0.f, 0.f};
            #pragma unroll
            for (int i = 0; i < 4; ++i) {
                const int row = i * 4 + rr4;
                __builtin_nontemporal_store(
                    z, reinterpret_cast<f32x4*>(attn + (bhS + l0 + row) * kS + k0 + cc4));
            }
            continue;
        }
        float sl[4][4];
        #pragma unroll
        for (int nt = 0; nt < 4; ++nt) {
            const ushort* krow = kh + (bhS + k0 + nt * 16 + n15) * kDH;
            f32x4 acc = {0.f, 0.f, 0.f, 0.f};
            acc = mfma16(aq0, *reinterpret_cast<const short8*>(krow + g * 8), acc);
            acc = mfma16(aq1, *reinterpret_cast<const short8*>(krow + 32 + g * 8), acc);
            #pragma unroll
            for (int j = 0; j < 4; ++j) sl[nt][j] = acc[j];
        }
        const int m_lo = 2032 + k0 - l0;
        f32x4 qe[5];
        #pragma unroll
        for (int nt = 0; nt < 5; ++nt) {
            int er = m_lo + nt * 16 + n15;
            if (er > kS - 1) er = kS - 1;
            const ushort* erow = eb + (size_t)er * kDH;
            f32x4 acc = {0.f, 0.f, 0.f, 0.f};
            acc = mfma16(aq0, *reinterpret_cast<const short8*>(erow + g * 8), acc);
            qe[nt] = mfma16(aq1, *reinterpret_cast<const short8*>(erow + 32 + g * 8), acc);
        }
        #pragma unroll
        for (int j = 0; j < 4; ++j) {
            float sh[5];
            #pragma unroll
            for (int q5 = 0; q5 < 5; ++q5) sh[q5] = __shfl(qe[q5][j], srcl[j]);
            const int lr = g * 4 + j;
            #pragma unroll
            for (int nt = 0; nt < 4; ++nt) {
                const float rel = condj[j] ? sh[nt + 1] : sh[nt];
                const int ki = nt * 16 + n15;
                float v = (sl[nt][j] + rel) * 0.125f;
                v = fminf(v, 60.f);
                const float pe = (k0 + ki <= l0 + lr) ? __expf(v) * linv[j] : 0.f;
                Pw[lr * 68 + ki] = pe;           // ds_write_b32, 2-way banks
            }
        }
        WAVE_LDS_FENCE();                        // Pw writes -> reads

        // (a) attn stores: 4 instrs, each 4 rows x 256B contiguous segments
        #pragma unroll
        for (int i = 0; i < 4; ++i) {
            const int row = i * 4 + rr4;
            const f32x4 pv4 = *reinterpret_cast<const f32x4*>(&Pw[row * 68 + cc4]);
            __builtin_nontemporal_store(
                pv4, reinterpret_cast<f32x4*>(attn + (bhS + l0 + row) * kS + k0 + cc4));
        }
        // (b) PV A-frags: row n15, keys g*8..+8 and 32+g*8..+8
        const f32x4 plo0 = *reinterpret_cast<const f32x4*>(&Pw[n15 * 68 + g * 8]);
        const f32x4 phi0 = *reinterpret_cast<const f32x4*>(&Pw[n15 * 68 + g * 8 + 4]);
        const f32x4 plo1 = *reinterpret_cast<const f32x4*>(&Pw[n15 * 68 + 32 + g * 8]);
        const f32x4 phi1 = *reinterpret_cast<const f32x4*>(&Pw[n15 * 68 + 32 + g * 8 + 4]);
        WAVE_LDS_FENCE();                        // Pw reads retired (WAR vs next tile)

        short8 pa0, pa1;
        #pragma unroll
        for (int i = 0; i < 4; ++i) {
            pa0[i] = bfbits(plo0[i]); pa0[4 + i] = bfbits(phi0[i]);
            pa1[i] = bfbits(plo1[i]); pa1[4 + i] = bfbits(phi1[i]);
        }
        #pragma unroll
        for (int nt = 0; nt < 4; ++nt) {
            const ushort* vrow = vt + ((size_t)bh * kDH + nt * 16 + n15) * kS + k0;
            o[nt] = mfma16(pa0, *reinterpret_cast<const short8*>(vrow + g * 8), o[nt]);
            o[nt] = mfma16(pa1, *reinterpret_cast<const short8*>(vrow + 32 + g * 8), o[nt]);
        }
    }

    // ---------------- O combine (O_s aliases Pw region) ----------------
    __syncthreads();                             // [barrier 2] all Pw reads done
    float* O_s = (float*)smem;                   // 4 waves x 16x64 f32 = 16 KiB
    #pragma unroll
    for (int nt = 0; nt < 4; ++nt)
        #pragma unroll
        for (int j = 0; j < 4; ++j)
            O_s[w * 1024 + (g * 4 + j) * 64 + nt * 16 + n15] = o[nt][j];
    __syncthreads();                             // [barrier 3]

    const int b = bh >> 3, h = bh & 7;
    #pragma unroll
    for (int i = tid; i < 1024; i += 256) {
        const int r = i >> 6, c = i & 63;
        const float acc = O_s[i] + O_s[1024 + i] + O_s[2048 + i] + O_s[3072 + i];
        ohb[((size_t)b * kS + l0 + r) * kD + h * kDH + c] = (ushort)bfbits(acc);
    }
}

// ---------------------------------------------------------------------------
extern "C" void kernel_launch(void* const* d_in, const int* in_sizes, int n_in,
                              void* d_out, int out_size, void* d_ws, size_t ws_size,
                              hipStream_t stream)
{
    const float* q_in = (const float*)d_in[0];
    const float* k_in = (const float*)d_in[1];
    const float* v_in = (const float*)d_in[2];
    const float* Wq = (const float*)d_in[4];
    const float* bq = (const float*)d_in[5];
    const float* Wk = (const float*)d_in[6];
    const float* bk = (const float*)d_in[7];
    const float* Wv = (const float*)d_in[8];
    const float* bv = (const float*)d_in[9];
    const float* Wo = (const float*)d_in[10];
    const float* bo = (const float*)d_in[11];
    const float* E  = (const float*)d_in[12];

    float* out  = (float*)d_out;                          // (B,S,D)
    float* attn = (float*)d_out + (size_t)kB * kS * kD;   // (B,H,S,S)

    // workspace: all bf16 (~31.7 MB)
    ushort* qh  = (ushort*)d_ws;          // (B,H,S,DH)
    ushort* kh  = qh  + 2097152;          // (B,H,S,DH)
    ushort* vt  = kh  + 2097152;          // (B,H,DH,S)
    ushort* ohb = vt  + 2097152;          // (B,S,D)
    ushort* qb  = ohb + 2097152;          // (B,S,D) inputs in bf16
    ushort* kb  = qb  + 2097152;
    ushort* vb  = kb  + 2097152;
    ushort* eb  = vb  + 2097152;          // (2048,64)
    ushort* Wqt = eb  + 131072;           // col-major 512x512
    ushort* Wkt = Wqt + 262144;
    ushort* Wvt = Wkt + 262144;
    ushort* Wot = Wvt + 262144;

    convw_kernel<<<dim3(8, 8, 5), 256, 0, stream>>>(Wq, Wk, Wv, Wo, E,
                                                    Wqt, Wkt, Wvt, Wot, eb);
    cvta_kernel<<<dim3(1024, 1, 3), 256, 0, stream>>>(q_in, k_in, v_in, qb, kb, vb);
    gemm_qkv_kernel<<<dim3(64, 16, 3), 256, 0, stream>>>(qb, kb, vb,
                                                         Wqt, Wkt, Wvt,
                                                         bq, bk, bv, qh, kh, vt);
    attn_fused_kernel<<<dim3(16, 128), 256, 0, stream>>>(qh, kh, vt, eb, attn, ohb);
    gemm_o_kernel<<<dim3(64, 16), 256, 0, stream>>>(ohb, Wot, bo, out);
}